// Round 1
// baseline (343.493 us; speedup 1.0000x reference)
//
#include <hip/hip_runtime.h>
#include <stdint.h>
#include <stddef.h>

#define DIM 768
#define NH  12
#define NKV 4
#define HD  64
#define TT  128
#define NS  256

typedef __attribute__((ext_vector_type(8))) short bf16x8;
typedef __attribute__((ext_vector_type(4))) float f32x4;
typedef __attribute__((ext_vector_type(4))) unsigned int u32x4;
typedef __attribute__((ext_vector_type(2))) unsigned int u32x2;

__device__ __forceinline__ unsigned short f2bf(float f) {
  union { float f; unsigned int u; } v; v.f = f;
  return (unsigned short)((v.u + 0x7FFFu + ((v.u >> 16) & 1u)) >> 16);
}

// ---------------- kernel 0: weight prep (transpose + bf16) ----------------
// Wt: 1280 rows (cols of [Wq|Wk|Wv]) x 768 k.  WoT: 768 rows (cols of Wo) x 768 k.
__global__ __launch_bounds__(256)
void prep_weights(const float* __restrict__ Wq, const float* __restrict__ Wk,
                  const float* __restrict__ Wv, const float* __restrict__ Wo,
                  unsigned short* __restrict__ Wt, unsigned short* __restrict__ WoT) {
  int idx = blockIdx.x * 256 + threadIdx.x;
  const int n1 = 1280 * DIM;
  if (idx < n1) {
    int c = idx / DIM, kk = idx - c * DIM;
    float v;
    if (c < 768)       v = Wq[kk * 768 + c];
    else if (c < 1024) v = Wk[kk * 256 + (c - 768)];
    else               v = Wv[kk * 256 + (c - 1024)];
    Wt[idx] = f2bf(v);
  } else {
    int i2 = idx - n1;
    if (i2 < 768 * DIM) {
      int c = i2 / DIM, kk = i2 - c * DIM;
      WoT[i2] = f2bf(Wo[kk * 768 + c]);
    }
  }
}

// ---------------- kernel 1: QKV projection + QKNorm ----------------
// Grid (10, 256): blockIdx.x = col-block (128 wide), blockIdx.y = n (spatial).
// Tile: 128 rows (t) x 128 cols. BK=64. cb 0..5 -> q heads 2cb,2cb+1;
// cb 6,7 -> k kv-heads; cb 8,9 -> v kv-heads (stored transposed).
__global__ __launch_bounds__(256)
void qkv_kernel(const float* __restrict__ x, const float* __restrict__ qnw,
                const float* __restrict__ knw, const unsigned short* __restrict__ Wt,
                unsigned short* __restrict__ qb, unsigned short* __restrict__ kb,
                unsigned short* __restrict__ vTb) {
  const int cb = blockIdx.x;
  const int n  = blockIdx.y;
  const int tid = threadIdx.x;
  const int wave = tid >> 6, lane = tid & 63;
  const int cl = lane & 15, rowg = lane >> 4;
  __shared__ unsigned short As[128][72];
  __shared__ unsigned short Bs[128][72];
  f32x4 acc[2][8] = {};
  const int col0 = cb * 128;
  for (int ko = 0; ko < DIM; ko += 64) {
    __syncthreads();
    // A: x rows t=0..127, cols ko..ko+63 (fp32 -> bf16). x[(t*NS+n)*DIM + d].
    #pragma unroll
    for (int i = 0; i < 8; ++i) {
      int c = tid + 256 * i;          // 2048 chunks of 4 floats
      int row = c >> 4, seg = c & 15;
      const f32x4* src = reinterpret_cast<const f32x4*>(
          x + (size_t)(row * NS + n) * DIM + ko + seg * 4);
      f32x4 f = *src;
      u32x2 pk;
      pk[0] = (unsigned)f2bf(f[0]) | ((unsigned)f2bf(f[1]) << 16);
      pk[1] = (unsigned)f2bf(f[2]) | ((unsigned)f2bf(f[3]) << 16);
      *reinterpret_cast<u32x2*>(&As[row][seg * 4]) = pk;
    }
    // B: Wt rows col0..col0+127, 64 bf16 each (contiguous)
    #pragma unroll
    for (int i = 0; i < 4; ++i) {
      int c = tid + 256 * i;          // 1024 chunks of 8 bf16
      int r = c >> 3, seg = c & 7;
      *reinterpret_cast<u32x4*>(&Bs[r][seg * 8]) =
          *reinterpret_cast<const u32x4*>(Wt + (size_t)(col0 + r) * DIM + ko + seg * 8);
    }
    __syncthreads();
    #pragma unroll
    for (int ks = 0; ks < 2; ++ks) {
      bf16x8 a[2], b[8];
      #pragma unroll
      for (int m = 0; m < 2; ++m)
        a[m] = *reinterpret_cast<const bf16x8*>(&As[wave * 32 + m * 16 + cl][ks * 32 + rowg * 8]);
      #pragma unroll
      for (int nn = 0; nn < 8; ++nn)
        b[nn] = *reinterpret_cast<const bf16x8*>(&Bs[nn * 16 + cl][ks * 32 + rowg * 8]);
      #pragma unroll
      for (int m = 0; m < 2; ++m)
        #pragma unroll
        for (int nn = 0; nn < 8; ++nn)
          acc[m][nn] = __builtin_amdgcn_mfma_f32_16x16x32_bf16(a[m], b[nn], acc[m][nn], 0, 0, 0);
    }
  }
  // Epilogue: per-64-col-half RMSNorm (q,k) or transpose store (v).
  const int typ = (cb < 6) ? 0 : (cb < 8 ? 1 : 2);
  float wfrag[4];
  #pragma unroll
  for (int nn4 = 0; nn4 < 4; ++nn4)
    wfrag[nn4] = (typ == 0) ? qnw[nn4 * 16 + cl] : (typ == 1 ? knw[nn4 * 16 + cl] : 1.0f);
  #pragma unroll
  for (int half = 0; half < 2; ++half) {
    #pragma unroll
    for (int m = 0; m < 2; ++m) {
      #pragma unroll
      for (int j = 0; j < 4; ++j) {
        const int t = wave * 32 + m * 16 + rowg * 4 + j;
        if (typ == 2) {
          const int kv = (cb - 8) * 2 + half;
          unsigned short* dst = vTb + (size_t)((n * NKV + kv) * HD) * TT;
          #pragma unroll
          for (int nn4 = 0; nn4 < 4; ++nn4) {
            int d = nn4 * 16 + cl;
            dst[(size_t)d * TT + t] = f2bf(acc[m][half * 4 + nn4][j]);
          }
        } else {
          float ss = 0.f;
          #pragma unroll
          for (int nn4 = 0; nn4 < 4; ++nn4) {
            float v = acc[m][half * 4 + nn4][j];
            ss += v * v;
          }
          #pragma unroll
          for (int dlt = 1; dlt < 16; dlt <<= 1) ss += __shfl_xor(ss, dlt);
          float r = rsqrtf(ss * (1.f / 64.f) + 1e-6f);
          if (typ == 0) {
            r *= 0.125f;  // fold attention SCALE into q
            const int hh = cb * 2 + half;
            unsigned short* dst = qb + ((size_t)(n * NH + hh) * TT + t) * HD;
            #pragma unroll
            for (int nn4 = 0; nn4 < 4; ++nn4)
              dst[nn4 * 16 + cl] = f2bf(acc[m][half * 4 + nn4][j] * r * wfrag[nn4]);
          } else {
            const int kv = (cb - 6) * 2 + half;
            unsigned short* dst = kb + ((size_t)(n * NKV + kv) * TT + t) * HD;
            #pragma unroll
            for (int nn4 = 0; nn4 < 4; ++nn4)
              dst[nn4 * 16 + cl] = f2bf(acc[m][half * 4 + nn4][j] * r * wfrag[nn4]);
          }
        }
      }
    }
  }
}

// ---------------- kernel 2: attention per (n, h) ----------------
__global__ __launch_bounds__(256)
void attn_kernel(const unsigned short* __restrict__ qb, const unsigned short* __restrict__ kb,
                 const unsigned short* __restrict__ vTb, unsigned short* __restrict__ ab) {
  const int h = blockIdx.x, n = blockIdx.y;
  const int kv = h / 3;
  const int tid = threadIdx.x, wave = tid >> 6, lane = tid & 63;
  const int cl = lane & 15, rowg = lane >> 4;
  __shared__ __align__(16) char smem[52224];
  unsigned short (*Qs)[72]  = reinterpret_cast<unsigned short (*)[72]>(smem);
  unsigned short (*Ks)[72]  = reinterpret_cast<unsigned short (*)[72]>(smem + 18432);
  unsigned short (*Pl)[136] = reinterpret_cast<unsigned short (*)[136]>(smem);
  unsigned short (*Vts)[136] = reinterpret_cast<unsigned short (*)[136]>(smem + 34816);

  const unsigned short* qsrc = qb + (size_t)(n * NH + h) * TT * HD;
  const unsigned short* ksrc = kb + (size_t)(n * NKV + kv) * TT * HD;
  #pragma unroll
  for (int i = 0; i < 4; ++i) {
    int c = tid + 256 * i, r = c >> 3, seg = c & 7;
    *reinterpret_cast<u32x4*>(&Qs[r][seg * 8]) = *reinterpret_cast<const u32x4*>(qsrc + c * 8);
  }
  #pragma unroll
  for (int i = 0; i < 4; ++i) {
    int c = tid + 256 * i, r = c >> 3, seg = c & 7;
    *reinterpret_cast<u32x4*>(&Ks[r][seg * 8]) = *reinterpret_cast<const u32x4*>(ksrc + c * 8);
  }
  __syncthreads();
  f32x4 sc[2][8] = {};
  #pragma unroll
  for (int ks = 0; ks < 2; ++ks) {
    bf16x8 a[2], b[8];
    #pragma unroll
    for (int m = 0; m < 2; ++m)
      a[m] = *reinterpret_cast<const bf16x8*>(&Qs[wave * 32 + m * 16 + cl][ks * 32 + rowg * 8]);
    #pragma unroll
    for (int nn = 0; nn < 8; ++nn)
      b[nn] = *reinterpret_cast<const bf16x8*>(&Ks[nn * 16 + cl][ks * 32 + rowg * 8]);
    #pragma unroll
    for (int m = 0; m < 2; ++m)
      #pragma unroll
      for (int nn = 0; nn < 8; ++nn)
        sc[m][nn] = __builtin_amdgcn_mfma_f32_16x16x32_bf16(a[m], b[nn], sc[m][nn], 0, 0, 0);
  }
  __syncthreads();  // Qs/Ks dead; their LDS is reused by Pl/Vts below
  // stage V^T (rows d=0..63, 128 t each, contiguous)
  const unsigned short* vsrc = vTb + (size_t)(n * NKV + kv) * HD * TT;
  #pragma unroll
  for (int i = 0; i < 4; ++i) {
    int c = tid + 256 * i, r = c >> 4, seg = c & 15;
    *reinterpret_cast<u32x4*>(&Vts[r][seg * 8]) = *reinterpret_cast<const u32x4*>(vsrc + c * 8);
  }
  // soft-cap + causal mask + softmax (rows live in 16-lane groups)
  #pragma unroll
  for (int m = 0; m < 2; ++m) {
    #pragma unroll
    for (int j = 0; j < 4; ++j) {
      const int rowv = wave * 32 + m * 16 + rowg * 4 + j;
      float mx = -__builtin_inff();
      #pragma unroll
      for (int nn = 0; nn < 8; ++nn) {
        float s = sc[m][nn][j];
        s = 50.f * tanhf(s * 0.02f);
        if (nn * 16 + cl > rowv) s = -__builtin_inff();
        sc[m][nn][j] = s;
        mx = fmaxf(mx, s);
      }
      #pragma unroll
      for (int d = 1; d < 16; d <<= 1) mx = fmaxf(mx, __shfl_xor(mx, d));
      float sum = 0.f;
      #pragma unroll
      for (int nn = 0; nn < 8; ++nn) {
        float e = __expf(sc[m][nn][j] - mx);
        sc[m][nn][j] = e;
        sum += e;
      }
      #pragma unroll
      for (int d = 1; d < 16; d <<= 1) sum += __shfl_xor(sum, d);
      const float inv = 1.f / sum;
      #pragma unroll
      for (int nn = 0; nn < 8; ++nn)
        Pl[rowv][nn * 16 + cl] = f2bf(sc[m][nn][j] * inv);
    }
  }
  __syncthreads();
  // PV: O[t][d] = sum_s P[t][s] V[s][d]
  f32x4 o[2][4] = {};
  #pragma unroll
  for (int ks = 0; ks < 4; ++ks) {
    bf16x8 a[2], b[4];
    #pragma unroll
    for (int m = 0; m < 2; ++m)
      a[m] = *reinterpret_cast<const bf16x8*>(&Pl[wave * 32 + m * 16 + cl][ks * 32 + rowg * 8]);
    #pragma unroll
    for (int nn = 0; nn < 4; ++nn)
      b[nn] = *reinterpret_cast<const bf16x8*>(&Vts[nn * 16 + cl][ks * 32 + rowg * 8]);
    #pragma unroll
    for (int m = 0; m < 2; ++m)
      #pragma unroll
      for (int nn = 0; nn < 4; ++nn)
        o[m][nn] = __builtin_amdgcn_mfma_f32_16x16x32_bf16(a[m], b[nn], o[m][nn], 0, 0, 0);
  }
  unsigned short* dst = ab + (size_t)n * TT * 768 + h * 64;
  #pragma unroll
  for (int m = 0; m < 2; ++m)
    #pragma unroll
    for (int j = 0; j < 4; ++j) {
      int t = wave * 32 + m * 16 + rowg * 4 + j;
      #pragma unroll
      for (int nn = 0; nn < 4; ++nn)
        dst[(size_t)t * 768 + nn * 16 + cl] = f2bf(o[m][nn][j]);
    }
}

// ---------------- kernel 3: output projection ----------------
__global__ __launch_bounds__(256)
void out_kernel(const unsigned short* __restrict__ ab, const unsigned short* __restrict__ WoT,
                float* __restrict__ out) {
  const int cb = blockIdx.x;  // 0..5
  const int n  = blockIdx.y;  // 0..255
  const int tid = threadIdx.x, wave = tid >> 6, lane = tid & 63;
  const int cl = lane & 15, rowg = lane >> 4;
  __shared__ unsigned short As[128][72];
  __shared__ unsigned short Bs[128][72];
  f32x4 acc[2][8] = {};
  for (int ko = 0; ko < DIM; ko += 64) {
    __syncthreads();
    #pragma unroll
    for (int i = 0; i < 4; ++i) {
      int c = tid + 256 * i, r = c >> 3, seg = c & 7;
      *reinterpret_cast<u32x4*>(&As[r][seg * 8]) =
          *reinterpret_cast<const u32x4*>(ab + (size_t)(n * TT + r) * DIM + ko + seg * 8);
    }
    #pragma unroll
    for (int i = 0; i < 4; ++i) {
      int c = tid + 256 * i, r = c >> 3, seg = c & 7;
      *reinterpret_cast<u32x4*>(&Bs[r][seg * 8]) =
          *reinterpret_cast<const u32x4*>(WoT + (size_t)(cb * 128 + r) * DIM + ko + seg * 8);
    }
    __syncthreads();
    #pragma unroll
    for (int ks = 0; ks < 2; ++ks) {
      bf16x8 a[2], b[8];
      #pragma unroll
      for (int m = 0; m < 2; ++m)
        a[m] = *reinterpret_cast<const bf16x8*>(&As[wave * 32 + m * 16 + cl][ks * 32 + rowg * 8]);
      #pragma unroll
      for (int nn = 0; nn < 8; ++nn)
        b[nn] = *reinterpret_cast<const bf16x8*>(&Bs[nn * 16 + cl][ks * 32 + rowg * 8]);
      #pragma unroll
      for (int m = 0; m < 2; ++m)
        #pragma unroll
        for (int nn = 0; nn < 8; ++nn)
          acc[m][nn] = __builtin_amdgcn_mfma_f32_16x16x32_bf16(a[m], b[nn], acc[m][nn], 0, 0, 0);
    }
  }
  // out[(t*S + n)*DIM + col], fp32
  #pragma unroll
  for (int m = 0; m < 2; ++m)
    #pragma unroll
    for (int j = 0; j < 4; ++j) {
      int t = wave * 32 + m * 16 + rowg * 4 + j;
      #pragma unroll
      for (int nn = 0; nn < 8; ++nn)
        out[(size_t)(t * NS + n) * DIM + cb * 128 + nn * 16 + cl] = acc[m][nn][j];
    }
}

// ---------------- launch ----------------
extern "C" void kernel_launch(void* const* d_in, const int* in_sizes, int n_in,
                              void* d_out, int out_size, void* d_ws, size_t ws_size,
                              hipStream_t stream) {
  const float* x   = (const float*)d_in[0];
  const float* Wq  = (const float*)d_in[1];
  const float* Wk  = (const float*)d_in[2];
  const float* Wv  = (const float*)d_in[3];
  const float* Wo  = (const float*)d_in[4];
  const float* qnw = (const float*)d_in[5];
  const float* knw = (const float*)d_in[6];
  (void)in_sizes; (void)n_in; (void)out_size;

  // workspace layout (bytes), all 16B aligned
  char* ws = (char*)d_ws;
  unsigned short* Wt  = (unsigned short*)(ws + 0);          // 1280*768*2   = 1,966,080
  unsigned short* WoT = (unsigned short*)(ws + 1966080);    // 768*768*2    = 1,179,648
  unsigned short* qb  = (unsigned short*)(ws + 3145728);    // 256*12*128*64*2 = 50,331,648
  unsigned short* kb  = (unsigned short*)(ws + 53477376);   // 256*4*128*64*2  = 16,777,216
  unsigned short* vTb = (unsigned short*)(ws + 70254592);   // 16,777,216
  unsigned short* ab  = (unsigned short*)(ws + 87031808);   // 32768*768*2  = 50,331,648
  if (ws_size < 137363456) return;  // insufficient scratch -> fail loudly at validation

  prep_weights<<<6144, 256, 0, stream>>>(Wq, Wk, Wv, Wo, Wt, WoT);
  qkv_kernel<<<dim3(10, 256), 256, 0, stream>>>(x, qnw, knw, Wt, qb, kb, vTb);
  attn_kernel<<<dim3(12, 256), 256, 0, stream>>>(qb, kb, vTb, ab);
  out_kernel<<<dim3(6, 256), 256, 0, stream>>>(ab, WoT, (float*)d_out);
}

// Round 2
// 239.872 us; speedup vs baseline: 1.4320x; 1.4320x over previous
//
#include <hip/hip_runtime.h>
#include <stdint.h>
#include <stddef.h>

#define DIM 768
#define NH  12
#define NKV 4
#define HD  64
#define TT  128
#define NS  256

typedef __attribute__((ext_vector_type(8))) short bf16x8;
typedef __attribute__((ext_vector_type(4))) float f32x4;
typedef __attribute__((ext_vector_type(4))) unsigned int u32x4;
typedef __attribute__((ext_vector_type(2))) unsigned int u32x2;

__device__ __forceinline__ unsigned short f2bf(float f) {
  union { float f; unsigned int u; } v; v.f = f;
  return (unsigned short)((v.u + 0x7FFFu + ((v.u >> 16) & 1u)) >> 16);
}

// ---------------- kernel 0: prep ----------------
// blocks [0,6144): weight transpose+bf16.  blocks [6144,30720): x fp32 -> bf16
// re-laid out as xb[(n*TT + t)*DIM + d] (contiguous 196KB slab per n).
__global__ __launch_bounds__(256)
void prep_kernel(const float* __restrict__ x, const float* __restrict__ Wq,
                 const float* __restrict__ Wk, const float* __restrict__ Wv,
                 const float* __restrict__ Wo, unsigned short* __restrict__ Wt,
                 unsigned short* __restrict__ WoT, unsigned short* __restrict__ xb) {
  const int b = blockIdx.x, tid = threadIdx.x;
  if (b < 6144) {
    int idx = b * 256 + tid;
    const int n1 = 1280 * DIM;
    if (idx < n1) {
      int c = idx / DIM, kk = idx - c * DIM;
      float v;
      if (c < 768)       v = Wq[kk * 768 + c];
      else if (c < 1024) v = Wk[kk * 256 + (c - 768)];
      else               v = Wv[kk * 256 + (c - 1024)];
      Wt[idx] = f2bf(v);
    } else {
      int i2 = idx - n1;
      int c = i2 / DIM, kk = i2 - c * DIM;
      WoT[i2] = f2bf(Wo[kk * 768 + c]);
    }
  } else {
    // 6,291,456 chunks of 4 floats; chunk g covers x[g*4 .. g*4+3]
    int g = (b - 6144) * 256 + tid;
    int r = g / 192;                  // r = t*NS + n
    int k = g - r * 192;
    int t = r >> 8, n = r & 255;
    f32x4 f = *reinterpret_cast<const f32x4*>(x + (size_t)g * 4);
    u32x2 pk;
    pk[0] = (unsigned)f2bf(f[0]) | ((unsigned)f2bf(f[1]) << 16);
    pk[1] = (unsigned)f2bf(f[2]) | ((unsigned)f2bf(f[3]) << 16);
    *reinterpret_cast<u32x2*>(xb + (size_t)((n << 7) + t) * DIM + k * 4) = pk;
  }
}

// ---------------- kernel 1: QKV projection + QKNorm ----------------
// 2560 blocks, XCD-swizzled: xcd = b&7 serves n ≡ xcd (mod 8); the 10
// col-blocks of one n are consecutive on that XCD -> A slab L2-resident.
// Per-wave tile 64x64 (wr = wave>>1 rows, wc = wave&1 cols). Each wave's 64
// cols = exactly one head (or one kv head / v head).
__global__ __launch_bounds__(256)
void qkv_kernel(const unsigned short* __restrict__ xb, const float* __restrict__ qnw,
                const float* __restrict__ knw, const unsigned short* __restrict__ Wt,
                unsigned short* __restrict__ qb, unsigned short* __restrict__ kb,
                unsigned short* __restrict__ vTb) {
  const int b = blockIdx.x;
  const int x8 = b & 7, ib = b >> 3;
  const int cb = ib % 10;
  const int n  = (ib / 10) * 8 + x8;
  const int tid = threadIdx.x;
  const int wave = tid >> 6, lane = tid & 63;
  const int cl = lane & 15, rowg = lane >> 4;
  const int wr = wave >> 1, wc = wave & 1;
  __shared__ unsigned short As[128][72];
  __shared__ unsigned short Bs[128][72];
  f32x4 acc[4][4] = {};
  const int col0 = cb * 128;
  for (int ko = 0; ko < DIM; ko += 64) {
    __syncthreads();
    #pragma unroll
    for (int i2 = 0; i2 < 4; ++i2) {
      int c = tid + 256 * i2, r = c >> 3, seg = c & 7;
      *reinterpret_cast<u32x4*>(&As[r][seg * 8]) =
          *reinterpret_cast<const u32x4*>(xb + (size_t)(n * TT + r) * DIM + ko + seg * 8);
    }
    #pragma unroll
    for (int i2 = 0; i2 < 4; ++i2) {
      int c = tid + 256 * i2, r = c >> 3, seg = c & 7;
      *reinterpret_cast<u32x4*>(&Bs[r][seg * 8]) =
          *reinterpret_cast<const u32x4*>(Wt + (size_t)(col0 + r) * DIM + ko + seg * 8);
    }
    __syncthreads();
    #pragma unroll
    for (int ks = 0; ks < 2; ++ks) {
      bf16x8 a[4], bb[4];
      #pragma unroll
      for (int m = 0; m < 4; ++m)
        a[m] = *reinterpret_cast<const bf16x8*>(&As[wr * 64 + m * 16 + cl][ks * 32 + rowg * 8]);
      #pragma unroll
      for (int nn = 0; nn < 4; ++nn)
        bb[nn] = *reinterpret_cast<const bf16x8*>(&Bs[wc * 64 + nn * 16 + cl][ks * 32 + rowg * 8]);
      #pragma unroll
      for (int m = 0; m < 4; ++m)
        #pragma unroll
        for (int nn = 0; nn < 4; ++nn)
          acc[m][nn] = __builtin_amdgcn_mfma_f32_16x16x32_bf16(a[m], bb[nn], acc[m][nn], 0, 0, 0);
    }
  }
  const int typ = (cb < 6) ? 0 : (cb < 8 ? 1 : 2);
  if (typ == 2) {
    // V: store transposed vT[d][t]; lane's 4 j-values are consecutive t -> 8B store
    const int kv = (cb - 8) * 2 + wc;
    unsigned short* dst = vTb + (size_t)((n * NKV + kv) * HD) * TT;
    #pragma unroll
    for (int m = 0; m < 4; ++m) {
      const int tb = wr * 64 + m * 16 + rowg * 4;
      #pragma unroll
      for (int nn = 0; nn < 4; ++nn) {
        const int d = nn * 16 + cl;
        u32x2 pk;
        pk[0] = (unsigned)f2bf(acc[m][nn][0]) | ((unsigned)f2bf(acc[m][nn][1]) << 16);
        pk[1] = (unsigned)f2bf(acc[m][nn][2]) | ((unsigned)f2bf(acc[m][nn][3]) << 16);
        *reinterpret_cast<u32x2*>(dst + (size_t)d * TT + tb) = pk;
      }
    }
  } else {
    const float* nw = (typ == 0) ? qnw : knw;
    float wfrag[4];
    #pragma unroll
    for (int nn = 0; nn < 4; ++nn) wfrag[nn] = nw[nn * 16 + cl];
    const float rs = (typ == 0) ? 0.125f : 1.0f;  // fold attention SCALE into q
    unsigned short* dst;
    if (typ == 0) { const int hh = cb * 2 + wc; dst = qb + (size_t)(n * NH + hh) * TT * HD; }
    else          { const int kv = (cb - 6) * 2 + wc; dst = kb + (size_t)(n * NKV + kv) * TT * HD; }
    #pragma unroll
    for (int m = 0; m < 4; ++m) {
      #pragma unroll
      for (int j = 0; j < 4; ++j) {
        const int t = wr * 64 + m * 16 + rowg * 4 + j;
        float ss = 0.f;
        #pragma unroll
        for (int nn = 0; nn < 4; ++nn) { float v = acc[m][nn][j]; ss += v * v; }
        #pragma unroll
        for (int dlt = 1; dlt < 16; dlt <<= 1) ss += __shfl_xor(ss, dlt);
        const float r = rsqrtf(ss * (1.f / 64.f) + 1e-6f) * rs;
        #pragma unroll
        for (int nn = 0; nn < 4; ++nn)
          dst[(size_t)t * HD + nn * 16 + cl] = f2bf(acc[m][nn][j] * r * wfrag[nn]);
      }
    }
  }
}

// ---------------- kernel 2: attention per (n, h) ----------------
__global__ __launch_bounds__(256)
void attn_kernel(const unsigned short* __restrict__ qb, const unsigned short* __restrict__ kb,
                 const unsigned short* __restrict__ vTb, unsigned short* __restrict__ ab) {
  const int b = blockIdx.x;
  const int x8 = b & 7, ib = b >> 3;
  const int h = ib % 12;
  const int n = (ib / 12) * 8 + x8;
  const int kv = h / 3;
  const int tid = threadIdx.x, wave = tid >> 6, lane = tid & 63;
  const int cl = lane & 15, rowg = lane >> 4;
  __shared__ __align__(16) char smem[52224];
  unsigned short (*Qs)[72]  = reinterpret_cast<unsigned short (*)[72]>(smem);
  unsigned short (*Ks)[72]  = reinterpret_cast<unsigned short (*)[72]>(smem + 18432);
  unsigned short (*Pl)[136] = reinterpret_cast<unsigned short (*)[136]>(smem);
  unsigned short (*Vts)[136] = reinterpret_cast<unsigned short (*)[136]>(smem + 34816);

  const unsigned short* qsrc = qb + (size_t)(n * NH + h) * TT * HD;
  const unsigned short* ksrc = kb + (size_t)(n * NKV + kv) * TT * HD;
  #pragma unroll
  for (int i = 0; i < 4; ++i) {
    int c = tid + 256 * i, r = c >> 3, seg = c & 7;
    *reinterpret_cast<u32x4*>(&Qs[r][seg * 8]) = *reinterpret_cast<const u32x4*>(qsrc + c * 8);
  }
  #pragma unroll
  for (int i = 0; i < 4; ++i) {
    int c = tid + 256 * i, r = c >> 3, seg = c & 7;
    *reinterpret_cast<u32x4*>(&Ks[r][seg * 8]) = *reinterpret_cast<const u32x4*>(ksrc + c * 8);
  }
  __syncthreads();
  f32x4 sc[2][8] = {};
  #pragma unroll
  for (int ks = 0; ks < 2; ++ks) {
    bf16x8 a[2], bbf[8];
    #pragma unroll
    for (int m = 0; m < 2; ++m)
      a[m] = *reinterpret_cast<const bf16x8*>(&Qs[wave * 32 + m * 16 + cl][ks * 32 + rowg * 8]);
    #pragma unroll
    for (int nn = 0; nn < 8; ++nn)
      bbf[nn] = *reinterpret_cast<const bf16x8*>(&Ks[nn * 16 + cl][ks * 32 + rowg * 8]);
    #pragma unroll
    for (int m = 0; m < 2; ++m)
      #pragma unroll
      for (int nn = 0; nn < 8; ++nn)
        sc[m][nn] = __builtin_amdgcn_mfma_f32_16x16x32_bf16(a[m], bbf[nn], sc[m][nn], 0, 0, 0);
  }
  __syncthreads();  // Qs/Ks dead; LDS reused by Pl/Vts
  const unsigned short* vsrc = vTb + (size_t)(n * NKV + kv) * HD * TT;
  #pragma unroll
  for (int i = 0; i < 4; ++i) {
    int c = tid + 256 * i, r = c >> 4, seg = c & 15;
    *reinterpret_cast<u32x4*>(&Vts[r][seg * 8]) = *reinterpret_cast<const u32x4*>(vsrc + c * 8);
  }
  // soft cap (rcp form) + causal mask + softmax; rows live in 16-lane groups
  #pragma unroll
  for (int m = 0; m < 2; ++m) {
    #pragma unroll
    for (int j = 0; j < 4; ++j) {
      const int rowv = wave * 32 + m * 16 + rowg * 4 + j;
      float mx = -__builtin_inff();
      #pragma unroll
      for (int nn = 0; nn < 8; ++nn) {
        float s = sc[m][nn][j];
        // 50*tanh(s/50) = 50 - 100/(exp(0.04*s)+1)
        float e = __expf(s * 0.04f);
        s = 50.f - 100.f * __builtin_amdgcn_rcpf(e + 1.f);
        if (nn * 16 + cl > rowv) s = -__builtin_inff();
        sc[m][nn][j] = s;
        mx = fmaxf(mx, s);
      }
      #pragma unroll
      for (int d = 1; d < 16; d <<= 1) mx = fmaxf(mx, __shfl_xor(mx, d));
      float sum = 0.f;
      #pragma unroll
      for (int nn = 0; nn < 8; ++nn) {
        float e = __expf(sc[m][nn][j] - mx);
        sc[m][nn][j] = e;
        sum += e;
      }
      #pragma unroll
      for (int d = 1; d < 16; d <<= 1) sum += __shfl_xor(sum, d);
      const float inv = __builtin_amdgcn_rcpf(sum);
      #pragma unroll
      for (int nn = 0; nn < 8; ++nn)
        Pl[rowv][nn * 16 + cl] = f2bf(sc[m][nn][j] * inv);
    }
  }
  __syncthreads();
  f32x4 o[2][4] = {};
  #pragma unroll
  for (int ks = 0; ks < 4; ++ks) {
    bf16x8 a[2], bbf[4];
    #pragma unroll
    for (int m = 0; m < 2; ++m)
      a[m] = *reinterpret_cast<const bf16x8*>(&Pl[wave * 32 + m * 16 + cl][ks * 32 + rowg * 8]);
    #pragma unroll
    for (int nn = 0; nn < 4; ++nn)
      bbf[nn] = *reinterpret_cast<const bf16x8*>(&Vts[nn * 16 + cl][ks * 32 + rowg * 8]);
    #pragma unroll
    for (int m = 0; m < 2; ++m)
      #pragma unroll
      for (int nn = 0; nn < 4; ++nn)
        o[m][nn] = __builtin_amdgcn_mfma_f32_16x16x32_bf16(a[m], bbf[nn], o[m][nn], 0, 0, 0);
  }
  unsigned short* dst = ab + (size_t)n * TT * 768 + h * 64;
  #pragma unroll
  for (int m = 0; m < 2; ++m)
    #pragma unroll
    for (int j = 0; j < 4; ++j) {
      int t = wave * 32 + m * 16 + rowg * 4 + j;
      #pragma unroll
      for (int nn = 0; nn < 4; ++nn)
        dst[(size_t)t * 768 + nn * 16 + cl] = f2bf(o[m][nn][j]);
    }
}

// ---------------- kernel 3: output projection ----------------
__global__ __launch_bounds__(256)
void out_kernel(const unsigned short* __restrict__ ab, const unsigned short* __restrict__ WoT,
                float* __restrict__ out) {
  const int b = blockIdx.x;
  const int x8 = b & 7, ib = b >> 3;
  const int cb = ib % 6;
  const int n  = (ib / 6) * 8 + x8;
  const int tid = threadIdx.x, wave = tid >> 6, lane = tid & 63;
  const int cl = lane & 15, rowg = lane >> 4;
  const int wr = wave >> 1, wc = wave & 1;
  __shared__ unsigned short As[128][72];
  __shared__ unsigned short Bs[128][72];
  f32x4 acc[4][4] = {};
  for (int ko = 0; ko < DIM; ko += 64) {
    __syncthreads();
    #pragma unroll
    for (int i2 = 0; i2 < 4; ++i2) {
      int c = tid + 256 * i2, r = c >> 3, seg = c & 7;
      *reinterpret_cast<u32x4*>(&As[r][seg * 8]) =
          *reinterpret_cast<const u32x4*>(ab + (size_t)(n * TT + r) * DIM + ko + seg * 8);
    }
    #pragma unroll
    for (int i2 = 0; i2 < 4; ++i2) {
      int c = tid + 256 * i2, r = c >> 3, seg = c & 7;
      *reinterpret_cast<u32x4*>(&Bs[r][seg * 8]) =
          *reinterpret_cast<const u32x4*>(WoT + (size_t)(cb * 128 + r) * DIM + ko + seg * 8);
    }
    __syncthreads();
    #pragma unroll
    for (int ks = 0; ks < 2; ++ks) {
      bf16x8 a[4], bb[4];
      #pragma unroll
      for (int m = 0; m < 4; ++m)
        a[m] = *reinterpret_cast<const bf16x8*>(&As[wr * 64 + m * 16 + cl][ks * 32 + rowg * 8]);
      #pragma unroll
      for (int nn = 0; nn < 4; ++nn)
        bb[nn] = *reinterpret_cast<const bf16x8*>(&Bs[wc * 64 + nn * 16 + cl][ks * 32 + rowg * 8]);
      #pragma unroll
      for (int m = 0; m < 4; ++m)
        #pragma unroll
        for (int nn = 0; nn < 4; ++nn)
          acc[m][nn] = __builtin_amdgcn_mfma_f32_16x16x32_bf16(a[m], bb[nn], acc[m][nn], 0, 0, 0);
    }
  }
  #pragma unroll
  for (int m = 0; m < 4; ++m)
    #pragma unroll
    for (int j = 0; j < 4; ++j) {
      int t = wr * 64 + m * 16 + rowg * 4 + j;
      #pragma unroll
      for (int nn = 0; nn < 4; ++nn)
        out[(size_t)(t * NS + n) * DIM + cb * 128 + wc * 64 + nn * 16 + cl] = acc[m][nn][j];
    }
}

// ---------------- launch ----------------
extern "C" void kernel_launch(void* const* d_in, const int* in_sizes, int n_in,
                              void* d_out, int out_size, void* d_ws, size_t ws_size,
                              hipStream_t stream) {
  const float* x   = (const float*)d_in[0];
  const float* Wq  = (const float*)d_in[1];
  const float* Wk  = (const float*)d_in[2];
  const float* Wv  = (const float*)d_in[3];
  const float* Wo  = (const float*)d_in[4];
  const float* qnw = (const float*)d_in[5];
  const float* knw = (const float*)d_in[6];
  (void)in_sizes; (void)n_in; (void)out_size;

  // workspace layout (bytes). xb ALIASES ab: qkv finishes reading xb before
  // attn writes ab (stream-serialized), keeping total at the proven 137 MB.
  char* ws = (char*)d_ws;
  unsigned short* Wt  = (unsigned short*)(ws + 0);          // 1,966,080
  unsigned short* WoT = (unsigned short*)(ws + 1966080);    // 1,179,648
  unsigned short* qb  = (unsigned short*)(ws + 3145728);    // 50,331,648
  unsigned short* kb  = (unsigned short*)(ws + 53477376);   // 16,777,216
  unsigned short* vTb = (unsigned short*)(ws + 70254592);   // 16,777,216
  unsigned short* ab  = (unsigned short*)(ws + 87031808);   // 50,331,648
  unsigned short* xb  = ab;                                 // alias (see above)
  if (ws_size < 137363456) return;

  prep_kernel<<<30720, 256, 0, stream>>>(x, Wq, Wk, Wv, Wo, Wt, WoT, xb);
  qkv_kernel<<<2560, 256, 0, stream>>>(xb, qnw, knw, Wt, qb, kb, vTb);
  attn_kernel<<<3072, 256, 0, stream>>>(qb, kb, vTb, ab);
  out_kernel<<<1536, 256, 0, stream>>>(ab, WoT, (float*)d_out);
}